// Round 3
// baseline (482.898 us; speedup 1.0000x reference)
//
#include <hip/hip_runtime.h>
#include <hip/hip_bf16.h>

// ComparatorNBit: A,B are [N,32] float32 in {0,1}, MSB first.
// a_eq_b = all bits equal; a_gt_b = unsigned compare of packed 32-bit words.
//
// R3: 2 chunks/thread (4 independent float4 loads in flight -> 2x MLP) and
// ballot-based cross-lane combine instead of the 6-deep shfl chain.
// Per lane: pack a nibble, diff=(an!=bn), gt=(an>bn). __ballot gives the
// wave's 8-row nibble masks to all lanes; row byte's lowest set bit is the
// most-significant differing nibble: a_gt = (t & (d & -d)) != 0, a_eq = d==0.
// R2 post-mortem: coalesced shfl version ~133 us (3.9 TB/s) — latency-bound
// on the serialized shfl chain + only 2 loads in flight. Floor ~84 us.

__global__ void __launch_bounds__(256)
comparator_kernel(const float4* __restrict__ A, const float4* __restrict__ B,
                  float* __restrict__ out_gt, float* __restrict__ out_eq,
                  long long nRows) {
    const long long base = (long long)blockIdx.x * 512 + threadIdx.x;
    const long long i0 = base;          // chunk 0 vec index
    const long long i1 = base + 256;    // chunk 1 vec index

    // 4 independent loads issued before any use.
    float4 a0 = A[i0];
    float4 b0 = B[i0];
    float4 a1 = A[i1];
    float4 b1 = B[i1];

    // Pack 4 consecutive elements into a nibble, MSB-first.
#define PACK(v) (((unsigned)((v).x > 0.5f) << 3) | ((unsigned)((v).y > 0.5f) << 2) | \
                 ((unsigned)((v).z > 0.5f) << 1) |  (unsigned)((v).w > 0.5f))
    unsigned an0 = PACK(a0), bn0 = PACK(b0);
    unsigned an1 = PACK(a1), bn1 = PACK(b1);
#undef PACK

    // Wave-wide nibble-compare masks. Lane 8g+k holds nibble k (k=0 is MSnib)
    // of row g, so within row g's byte the lowest set bit = most-significant
    // differing nibble.
    unsigned long long d0 = __ballot(an0 != bn0);
    unsigned long long t0 = __ballot(an0 > bn0);
    unsigned long long d1 = __ballot(an1 != bn1);
    unsigned long long t1 = __ballot(an1 > bn1);

    const int lane = threadIdx.x & 63;
    if (lane < 16) {
        const int g = lane & 7;
        const bool second = lane >= 8;
        unsigned long long d = second ? d1 : d0;
        unsigned long long t = second ? t1 : t0;
        unsigned db = (unsigned)(d >> (8 * g)) & 0xFFu;
        unsigned tb = (unsigned)(t >> (8 * g)) & 0xFFu;

        // Wave's chunk-0 first vec = blockIdx*512 + (tid & ~63); row = vec/8.
        const long long waveRow0 = ((long long)blockIdx.x * 512 + (threadIdx.x & 192)) >> 3;
        const long long row = waveRow0 + g + (second ? 32 : 0);

        if (row < nRows) {
            unsigned msdiff = db & (0u - db);           // isolate lowest set bit
            out_gt[row] = (tb & msdiff) ? 1.0f : 0.0f;
            out_eq[row] = (db == 0u)   ? 1.0f : 0.0f;
        }
    }
}

extern "C" void kernel_launch(void* const* d_in, const int* in_sizes, int n_in,
                              void* d_out, int out_size, void* d_ws, size_t ws_size,
                              hipStream_t stream) {
    const float4* A = (const float4*)d_in[0];
    const float4* B = (const float4*)d_in[1];
    float* out = (float*)d_out;

    const int BITS = 32;
    long long n = in_sizes[0] / BITS;      // 2,000,000 rows

    float* out_gt = out;                   // output 0: a_gt_b [N]
    float* out_eq = out + n;               // output 1: a_eq_b [N]

    long long totalVec = n * 8;            // float4s per input (16,000,000)
    // 512 vecs per block (256 threads x 2 chunks); N=2M divides exactly.
    long long grid = (totalVec + 511) / 512;
    comparator_kernel<<<(int)grid, 256, 0, stream>>>(A, B, out_gt, out_eq, n);
}